// Round 7
// baseline (236.245 us; speedup 1.0000x reference)
//
#include <hip/hip_runtime.h>
#include <hip/hip_bf16.h>

#define SLEN 2048
#define BATCH 2
#define NHQ 16
#define NHKV 8
#define DIM 128
#define SEG 512              // rows per segment (= chunk in this config)
#define NSEG (SLEN / SEG)    // 4
#define KVROW (NHKV * DIM)   // 1024 floats

#define KSTR 68              // dwords per K-tile row  (136 bf16 = 128 + 8 pad)
#define VSTR 36              // dwords per V^T row     (72 bf16  = 64 + 8 pad)
#define PSTR 72              // bf16 per P row         (64 + 8 pad)

typedef __attribute__((ext_vector_type(8))) short bf16x8;
typedef __attribute__((ext_vector_type(4))) float f32x4;

static __device__ inline short f2bf(float f) {
    __hip_bfloat16 h = __float2bfloat16(f);
    return *reinterpret_cast<short*>(&h);
}
static __device__ inline unsigned pack_bf2(float lo, float hi) {
    unsigned a = (unsigned)(unsigned short)f2bf(lo);
    unsigned b = (unsigned)(unsigned short)f2bf(hi);
    return a | (b << 16);
}

// ---------------------------------------------------------------------------
// Preprocess: run_start / run_end of the contiguous run of 1s containing s.
// rs=-1, re=-2 if mask[s]==0.  bidir-allowed(q,k) <=> rs[q]>=0 && rs[q]==rs[k]
// ---------------------------------------------------------------------------
__global__ void prep_runs(const int* __restrict__ mask,
                          int* __restrict__ rs, int* __restrict__ re) {
    __shared__ int sm[SLEN];
    const int b = blockIdx.x;
    const int* mb = mask + b * SLEN;
    for (int i = threadIdx.x; i < SLEN; i += blockDim.x) sm[i] = mb[i];
    __syncthreads();
    for (int i = threadIdx.x; i < SLEN; i += blockDim.x) {
        int s0 = -1, e0 = -2;
        if (sm[i] == 1) {
            s0 = i; while (s0 > 0 && sm[s0 - 1] == 1) --s0;
            e0 = i; while (e0 < SLEN - 1 && sm[e0 + 1] == 1) ++e0;
        }
        rs[b * SLEN + i] = s0;
        re[b * SLEN + i] = e0;
    }
}

// ---------------------------------------------------------------------------
// Chunk-resident MFMA flash attention, 2 barrier-domains/CU.
// Block = 256 thr = 4 waves = (b, hq, segment, phase). Phase ph owns row-tiles
// j = ph+4i (i=0..7); wave w owns jA=ph+4w and jB=ph+28-4w (jA+jB const =>
// balanced). Per 64-key tile: K(bf16,[key][d]) and V^T(bf16,[d][key]) staged
// once per block into single-buffered LDS; two barriers per tile; global
// prefetch for tile i+1 is in flight across tile i's compute phase.
// Grid = 512 = BATCH*NHKV*2*NSEG*4  (round-6 bug: launched 256 -> batch 1
// and half the (h,seg) combos never computed).
// ---------------------------------------------------------------------------
__global__ __launch_bounds__(256, 2) void attn_fwd(
    const float* __restrict__ Q, const float* __restrict__ K,
    const float* __restrict__ V, const int* __restrict__ rs,
    const int* __restrict__ re, const int* __restrict__ csp,
    float* __restrict__ Out)
{
    const int tid  = threadIdx.x;
    const int wid  = tid >> 6;     // 0..3
    const int lane = tid & 63;
    const int quad = lane >> 4;
    const int n    = lane & 15;

    // XCD swizzle: the 8 blocks sharing (b,h,seg) K/V land on one XCD
    const int bid = blockIdx.x;            // 0..511
    const int xcd = bid & 7;
    const int M   = (bid >> 3) & 7;        // (hq_low, phase)
    const int Ghi = bid >> 6;              // 0..7
    const int G   = Ghi * 8 + xcd;         // (b, h, seg) in 0..63
    const int seg = G & 3;
    const int h   = (G >> 2) & 7;
    const int b   = G >> 5;
    const int hq  = h * 2 + (M & 1);
    const int ph  = M >> 1;                // 0..3

    const int rbase = seg * SEG;
    int r0[2];
    r0[0] = rbase + (ph + 4 * wid) * 16;          // jA
    r0[1] = rbase + (ph + 28 - 4 * wid) * 16;     // jB  (jA+jB const)

    __shared__ unsigned kt[64 * KSTR];         // K tile, bf16 [key][d]
    __shared__ unsigned vt[128 * VSTR];        // V^T tile, bf16 [d][key]
    __shared__ short    pls[4][2][16 * PSTR];  // per-wave P tiles (bf16)
    __shared__ int      smk[64];               // per-tile rs[key]
    __shared__ int      wred[8];               // block lo/hi reduce

    // exp2-domain scale: 1/sqrt(128) * log2(e)
    const float scale = 0.08838834764831845f * 1.44269504088896340f;
    const int cs = csp[0];

    const int* rsb = rs + b * SLEN;
    const int* reb = re + b * SLEN;

    // per-row-tile k-range, run ids, chunk starts
    int lo_rt[2], hi_rt[2], rsrv[2][4], csg[2][4], cshi[2];
    #pragma unroll
    for (int u = 0; u < 2; ++u) {
        const int row = r0[u] + n;
        const int rsv = rsb[row];
        const int rev = reb[row];
        const int csr = (row / cs) * cs;
        int lo = csr; if (rsv >= 0 && rsv < lo) lo = rsv;
        int hi = row; if (rev > hi) hi = rev;
        #pragma unroll
        for (int off = 8; off > 0; off >>= 1) {
            lo = min(lo, __shfl_xor(lo, off, 64));
            hi = max(hi, __shfl_xor(hi, off, 64));
        }
        lo_rt[u] = lo; hi_rt[u] = hi;
        #pragma unroll
        for (int g = 0; g < 4; ++g) {
            const int r = r0[u] + quad * 4 + g;
            rsrv[u][g] = rsb[r];
            csg[u][g]  = (r / cs) * cs;
        }
        cshi[u] = ((r0[u] + 15) / cs) * cs;
    }

    // Q A-frags (scaled into exp2 domain): qa[u][kb], A[m=n][k=quad*8+j]
    bf16x8 qa[2][4];
    #pragma unroll
    for (int u = 0; u < 2; ++u) {
        const float* qp = Q + (((size_t)(b * SLEN + r0[u] + n) * NHQ + hq) * DIM) + quad * 8;
        #pragma unroll
        for (int kb = 0; kb < 4; ++kb) {
            float4 f0 = *(const float4*)(qp + kb * 32);
            float4 f1 = *(const float4*)(qp + kb * 32 + 4);
            bf16x8 a;
            a[0] = f2bf(f0.x * scale); a[1] = f2bf(f0.y * scale);
            a[2] = f2bf(f0.z * scale); a[3] = f2bf(f0.w * scale);
            a[4] = f2bf(f1.x * scale); a[5] = f2bf(f1.y * scale);
            a[6] = f2bf(f1.z * scale); a[7] = f2bf(f1.w * scale);
            qa[u][kb] = a;
        }
    }

    // block k-range = union over 4 waves
    if (lane == 0) {
        wred[wid * 2]     = min(lo_rt[0], lo_rt[1]);
        wred[wid * 2 + 1] = max(hi_rt[0], hi_rt[1]);
    }
    __syncthreads();
    int lo_blk = 0x7fffffff, hi_blk = 0;
    #pragma unroll
    for (int i = 0; i < 4; ++i) {
        lo_blk = min(lo_blk, wred[2 * i]);
        hi_blk = max(hi_blk, wred[2 * i + 1]);
    }
    lo_blk &= ~63;

    float mrow[2][4], lrow[2][4];
    f32x4 o[2][8];
    #pragma unroll
    for (int u = 0; u < 2; ++u) {
        #pragma unroll
        for (int g = 0; g < 4; ++g) { mrow[u][g] = -3.0e38f; lrow[u][g] = 0.0f; }
        #pragma unroll
        for (int nb = 0; nb < 8; ++nb) o[u][nb] = (f32x4){0.f, 0.f, 0.f, 0.f};
    }

    const float* Kb = K + ((size_t)b * SLEN * NHKV + h) * DIM;
    const float* Vb = V + ((size_t)b * SLEN * NHKV + h) * DIM;

    // staging roles (256 threads)
    // K: flat-coalesced — iter i: float4 index f=i*256+tid, row=f>>5, c4=f&31
    // V: vd = tid&127 (dim), vkh = (tid>>7)*32 (key half), 32 keys/thread
    const int vd  = tid & 127;
    const int vkh = (tid >> 7) * 32;

    float4 kr[8];
    float  vr[32];
    int    rsn = 0;

    // prime prefetch for first tile
    {
        const float* kp0 = Kb + (size_t)lo_blk * KVROW;
        const bool kin = (lo_blk + 64 <= SLEN);   // tile fully in-range?
        #pragma unroll
        for (int i = 0; i < 8; ++i) {
            const int f = i * 256 + tid;
            const int row = kin ? (f >> 5) : (min(lo_blk + (f >> 5), SLEN - 1) - lo_blk);
            kr[i] = *(const float4*)(kp0 + (size_t)row * KVROW + (f & 31) * 4);
        }
        #pragma unroll
        for (int i = 0; i < 32; ++i)
            vr[i] = Vb[(size_t)min(lo_blk + vkh + i, SLEN - 1) * KVROW + vd];
        if (tid < 64) rsn = rsb[min(lo_blk + tid, SLEN - 1)];
    }

    for (int k0 = lo_blk; k0 <= hi_blk; k0 += 64) {
        // ---- pack prefetched tile into LDS ----
        {
            #pragma unroll
            for (int i = 0; i < 8; ++i) {
                const int f = i * 256 + tid;
                uint2 w; w.x = pack_bf2(kr[i].x, kr[i].y); w.y = pack_bf2(kr[i].z, kr[i].w);
                *(uint2*)&kt[(f >> 5) * KSTR + (f & 31) * 2] = w;
            }
            uint4* vdst = (uint4*)&vt[vd * VSTR + (tid >> 7) * 16];
            #pragma unroll
            for (int m = 0; m < 4; ++m) {
                uint4 w;
                w.x = pack_bf2(vr[8 * m],     vr[8 * m + 1]);
                w.y = pack_bf2(vr[8 * m + 2], vr[8 * m + 3]);
                w.z = pack_bf2(vr[8 * m + 4], vr[8 * m + 5]);
                w.w = pack_bf2(vr[8 * m + 6], vr[8 * m + 7]);
                vdst[m] = w;
            }
            if (tid < 64) smk[tid] = rsn;
        }
        __syncthreads();   // B1: tile ready

        // ---- issue prefetch for next tile (lands during this compute) ----
        if (k0 + 64 <= hi_blk) {
            const int kn0 = k0 + 64;
            const float* kp0 = Kb + (size_t)kn0 * KVROW;
            const bool kin = (kn0 + 64 <= SLEN);
            #pragma unroll
            for (int i = 0; i < 8; ++i) {
                const int f = i * 256 + tid;
                const int row = kin ? (f >> 5) : (min(kn0 + (f >> 5), SLEN - 1) - kn0);
                kr[i] = *(const float4*)(kp0 + (size_t)row * KVROW + (f & 31) * 4);
            }
            #pragma unroll
            for (int i = 0; i < 32; ++i)
                vr[i] = Vb[(size_t)min(kn0 + vkh + i, SLEN - 1) * KVROW + vd];
            if (tid < 64) rsn = rsb[min(kn0 + tid, SLEN - 1)];
        }

        // ---- which of my 2 row-tiles touch this k-tile? (wave-uniform) ----
        bool act[2];
        act[0] = (k0 + 63 >= lo_rt[0]) && (k0 <= hi_rt[0]);
        act[1] = (k0 + 63 >= lo_rt[1]) && (k0 <= hi_rt[1]);

        if (act[0] || act[1]) {
            const short* ktb = (const short*)kt;
            const short* vtb = (const short*)vt;

            // ---- S = Q K^T, K-frag shared across both row-tiles ----
            f32x4 sfr[2][4];
            #pragma unroll
            for (int u = 0; u < 2; ++u)
                #pragma unroll
                for (int c = 0; c < 4; ++c)
                    sfr[u][c] = (f32x4){0.f, 0.f, 0.f, 0.f};
            #pragma unroll
            for (int c = 0; c < 4; ++c) {
                #pragma unroll
                for (int kb = 0; kb < 4; ++kb) {
                    bf16x8 kf = *(const bf16x8*)(ktb + (c * 16 + n) * 136 + kb * 32 + quad * 8);
                    if (act[0]) sfr[0][c] = __builtin_amdgcn_mfma_f32_16x16x32_bf16(qa[0][kb], kf, sfr[0][c], 0, 0, 0);
                    if (act[1]) sfr[1][c] = __builtin_amdgcn_mfma_f32_16x16x32_bf16(qa[1][kb], kf, sfr[1][c], 0, 0, 0);
                }
            }

            // ---- mask ----
            int rskv[4];
            #pragma unroll
            for (int c = 0; c < 4; ++c) rskv[c] = smk[c * 16 + n];
            #pragma unroll
            for (int u = 0; u < 2; ++u) {
                if (!act[u]) continue;
                const bool fullc = (k0 >= cshi[u]) && (k0 + 63 <= r0[u]);
                if (!fullc) {
                    #pragma unroll
                    for (int c = 0; c < 4; ++c) {
                        const int kcl = k0 + c * 16 + n;
                        const bool kin2 = (kcl < SLEN);
                        #pragma unroll
                        for (int g = 0; g < 4; ++g) {
                            const int r = r0[u] + quad * 4 + g;
                            const bool ok = kin2 && (((kcl >= csg[u][g]) && (kcl <= r)) ||
                                                     (rsrv[u][g] >= 0 && rskv[c] == rsrv[u][g]));
                            if (!ok) sfr[u][c][g] = -3.0e38f;
                        }
                    }
                }
            }

            // ---- online softmax (exp2 domain) + P store ----
            #pragma unroll
            for (int u = 0; u < 2; ++u) {
                if (!act[u]) continue;
                float mloc[4] = {-3.0e38f, -3.0e38f, -3.0e38f, -3.0e38f};
                #pragma unroll
                for (int c = 0; c < 4; ++c)
                    #pragma unroll
                    for (int g = 0; g < 4; ++g) mloc[g] = fmaxf(mloc[g], sfr[u][c][g]);
                #pragma unroll
                for (int off = 8; off > 0; off >>= 1)
                    #pragma unroll
                    for (int g = 0; g < 4; ++g)
                        mloc[g] = fmaxf(mloc[g], __shfl_xor(mloc[g], off, 64));

                float alpha[4];
                #pragma unroll
                for (int g = 0; g < 4; ++g) {
                    const float mnew = fmaxf(mrow[u][g], mloc[g]);
                    alpha[g] = exp2f(mrow[u][g] - mnew);
                    mrow[u][g] = mnew;
                }

                float psum[4] = {0.f, 0.f, 0.f, 0.f};
                #pragma unroll
                for (int c = 0; c < 4; ++c) {
                    #pragma unroll
                    for (int g = 0; g < 4; ++g) {
                        // masked: 2^(-3e38-m)=0 once m real; fully-masked rows
                        // carry p==1 garbage flushed by alpha==0 at diagonal.
                        const float pv = exp2f(sfr[u][c][g] - mrow[u][g]);
                        psum[g] += pv;
                        pls[wid][u][(quad * 4 + g) * PSTR + c * 16 + n] = f2bf(pv);
                    }
                }
                #pragma unroll
                for (int off = 8; off > 0; off >>= 1)
                    #pragma unroll
                    for (int g = 0; g < 4; ++g)
                        psum[g] += __shfl_xor(psum[g], off, 64);
                #pragma unroll
                for (int g = 0; g < 4; ++g)
                    lrow[u][g] = lrow[u][g] * alpha[g] + psum[g];
                #pragma unroll
                for (int nb = 0; nb < 8; ++nb)
                    #pragma unroll
                    for (int g = 0; g < 4; ++g)
                        o[u][nb][g] *= alpha[g];
            }

            // ---- O += P V, V-frag shared across both row-tiles ----
            #pragma unroll
            for (int kb2 = 0; kb2 < 2; ++kb2) {
                bf16x8 pa0, pa1;
                if (act[0]) pa0 = *(const bf16x8*)&pls[wid][0][n * PSTR + kb2 * 32 + quad * 8];
                if (act[1]) pa1 = *(const bf16x8*)&pls[wid][1][n * PSTR + kb2 * 32 + quad * 8];
                #pragma unroll
                for (int nb = 0; nb < 8; ++nb) {
                    bf16x8 vf = *(const bf16x8*)(vtb + (nb * 16 + n) * 72 + kb2 * 32 + quad * 8);
                    if (act[0]) o[0][nb] = __builtin_amdgcn_mfma_f32_16x16x32_bf16(pa0, vf, o[0][nb], 0, 0, 0);
                    if (act[1]) o[1][nb] = __builtin_amdgcn_mfma_f32_16x16x32_bf16(pa1, vf, o[1][nb], 0, 0, 0);
                }
            }
        }

        __syncthreads();   // B2: all reads of kt/vt/smk done; safe to repack
    }

    // ---- epilogue ----
    #pragma unroll
    for (int u = 0; u < 2; ++u) {
        #pragma unroll
        for (int g = 0; g < 4; ++g) {
            const float inv = 1.0f / lrow[u][g];
            const int r = r0[u] + quad * 4 + g;
            float* op = Out + ((size_t)(b * SLEN + r) * NHQ + hq) * DIM + n;
            #pragma unroll
            for (int nb = 0; nb < 8; ++nb)
                op[nb * 16] = o[u][nb][g] * inv;
        }
    }
}

extern "C" void kernel_launch(void* const* d_in, const int* in_sizes, int n_in,
                              void* d_out, int out_size, void* d_ws, size_t ws_size,
                              hipStream_t stream) {
    const float* q  = (const float*)d_in[0];
    const float* k  = (const float*)d_in[1];
    const float* v  = (const float*)d_in[2];
    const int*   bm = (const int*)d_in[3];
    const int*   cs = (const int*)d_in[4];
    float* out = (float*)d_out;

    int* rs = (int*)d_ws;
    int* re = rs + BATCH * SLEN;

    hipLaunchKernelGGL(prep_runs, dim3(BATCH), dim3(256), 0, stream, bm, rs, re);
    // 512 blocks = BATCH(2) x NHKV(8) x hq_low(2) x NSEG(4) x phase(4)
    hipLaunchKernelGGL(attn_fwd, dim3(BATCH * NHKV * 2 * NSEG * 4), dim3(256), 0, stream,
                       q, k, v, rs, re, cs, out);
}